// Round 1
// baseline (5251.636 us; speedup 1.0000x reference)
//
#include <hip/hip_runtime.h>

#define H     96    // hidden width of both MLPs
#define NOUT  32    // outputs of both MLPs (NUM_REP*2 == N_SCALARS == 32)
#define NSEG  97    // H+1 piecewise-linear segments
#define TPAD  128   // breakpoint array padded to pow2 for branchless search

// d_ws float layout:
//   [0      .. 127 ]  ts_msg  (sorted breakpoints, padded with +inf)
//   [128    .. 255 ]  ts_sc
//   [256    .. 3359]  A_msg [32][97]
//   [3360   .. 6463]  C_msg [32][97]   (includes +b2)
//   [6464   .. 9567]  A_sc  [32][97]
//   [9568   ..12671]  C_sc  [32][97]   (includes +b2)
//   [12672  ..12767]  rank_msg[96] (int)
//   [12768  ..12863]  rank_sc [96] (int)
#define WS_TS_MSG   0
#define WS_TS_SC    128
#define WS_TAB      256
#define WS_RANK     12672
#define TABSZ       (NOUT * NSEG)   // 3104

// ---------------------------------------------------------------------------
// P1: breakpoints t_j = -b1_j/w1_j, rank-sort (96 elems, O(96^2)), scatter
// sorted array (padded with +inf) and ranks into d_ws. One tiny block.
// ---------------------------------------------------------------------------
__global__ void build_breakpoints(const float* __restrict__ msg_w1,
                                  const float* __restrict__ msg_b1,
                                  const float* __restrict__ sc_w1,
                                  const float* __restrict__ sc_b1,
                                  float* __restrict__ ws) {
    __shared__ float t[2][H];
    const int tid = threadIdx.x;        // 192 threads
    const int mlp = tid / H;            // 0 = msg, 1 = sc (valid for tid<192)
    const int j   = tid % H;
    if (tid < 2 * H) {
        const float* w1 = mlp ? sc_w1 : msg_w1;
        const float* b1 = mlp ? sc_b1 : msg_b1;
        float w = w1[j], b = b1[j];
        t[mlp][j] = (w == 0.0f) ? __builtin_inff() : (-b / w);
    }
    __syncthreads();
    if (tid < 2 * H) {
        float tj = t[mlp][j];
        int r = 0;
        for (int i = 0; i < H; ++i) {
            float ti = t[mlp][i];
            r += (ti < tj) || (ti == tj && i < j);
        }
        float* ts = ws + (mlp ? WS_TS_SC : WS_TS_MSG);
        ts[r] = tj;
        ((int*)(ws + WS_RANK))[mlp * H + j] = r;
    }
    // pad indices 96..127 of both arrays with +inf
    if (tid < 2 * (TPAD - H)) {
        int m2 = tid / (TPAD - H);
        int p  = tid % (TPAD - H);
        ws[m2 * TPAD + H + p] = __builtin_inff();
    }
}

// ---------------------------------------------------------------------------
// P2: per (segment, mlp) block of 32 threads (one per output k), direct sum of
// active ReLU terms: j active in segment s iff
//   (w1_j > 0 && rank_j <  s) || (w1_j < 0 && rank_j >= s) || (w1_j==0 && b1_j>0)
// ---------------------------------------------------------------------------
__global__ void build_tables(const float* __restrict__ msg_w1,
                             const float* __restrict__ msg_b1,
                             const float* __restrict__ msg_w2,
                             const float* __restrict__ msg_b2,
                             const float* __restrict__ sc_w1,
                             const float* __restrict__ sc_b1,
                             const float* __restrict__ sc_w2,
                             const float* __restrict__ sc_b2,
                             float* __restrict__ ws) {
    const int s   = blockIdx.x;   // 0..96
    const int mlp = blockIdx.y;   // 0,1
    const int k   = threadIdx.x;  // 0..31
    const float* w1 = mlp ? sc_w1 : msg_w1;
    const float* b1 = mlp ? sc_b1 : msg_b1;
    const float* w2 = mlp ? sc_w2 : msg_w2;
    const float* b2 = mlp ? sc_b2 : msg_b2;
    const int* rank = (const int*)(ws + WS_RANK) + mlp * H;
    float A = 0.0f, C = 0.0f;
    for (int j = 0; j < H; ++j) {
        float w = w1[j], b = b1[j];
        int   r = rank[j];
        bool active = (w > 0.0f) ? (r < s)
                    : (w < 0.0f) ? (r >= s)
                                 : (b > 0.0f);
        if (active) {
            float wk = w2[j * NOUT + k];
            A = fmaf(w, wk, A);
            C = fmaf(b, wk, C);
        }
    }
    float* At = ws + WS_TAB + mlp * (2 * TABSZ);
    float* Ct = At + TABSZ;
    At[k * NSEG + s] = A;
    Ct[k * NSEG + s] = C + b2[k];
}

// ---------------------------------------------------------------------------
// Main: one thread per edge (grid-stride). Tables staged in LDS (~50.7 KB,
// 3 blocks/CU). Branchless lower_bound over padded-128 breakpoints, 32+32
// table FMAs, 2x2 rotation, 64 atomicAdds.
// ---------------------------------------------------------------------------
__global__ __launch_bounds__(256) void edge_kernel(
    const float* __restrict__ v, const float* __restrict__ rot,
    const int* __restrict__ ei, const float* __restrict__ ws,
    float* __restrict__ out, int E, int N)
{
    __shared__ float ts_m[TPAD], ts_s[TPAD];
    __shared__ float Am[TABSZ], Cm[TABSZ], As[TABSZ], Cs[TABSZ];
    for (int i = threadIdx.x; i < 256 + 4 * TABSZ; i += blockDim.x) {
        float val = ws[i];
        if      (i < 128)             ts_m[i]                 = val;
        else if (i < 256)             ts_s[i - 128]           = val;
        else if (i < 256 + TABSZ)     Am[i - 256]             = val;
        else if (i < 256 + 2*TABSZ)   Cm[i - 256 - TABSZ]     = val;
        else if (i < 256 + 3*TABSZ)   As[i - 256 - 2*TABSZ]   = val;
        else                          Cs[i - 256 - 3*TABSZ]   = val;
    }
    __syncthreads();

    const int* col_idx = ei + E;           // edge_index row 1
    float* out_sc  = out;
    float* out_rot = out + (size_t)N * 32;

    for (int e = blockIdx.x * blockDim.x + threadIdx.x; e < E;
         e += gridDim.x * blockDim.x) {
        float2 vv = *(const float2*)(v + 2 * (size_t)e);
        float  x  = sqrtf(vv.x * vv.x + vv.y * vv.y);
        float4 r  = *(const float4*)(rot + 4 * (size_t)e);
        int    col = col_idx[e];

        // seg = #{ t_i < x } via branchless lower_bound on padded-128 array
        int sm = 0;
        #pragma unroll
        for (int st = 64; st > 0; st >>= 1)
            if (ts_m[sm + st - 1] < x) sm += st;
        int ss = 0;
        #pragma unroll
        for (int st = 64; st > 0; st >>= 1)
            if (ts_s[ss + st - 1] < x) ss += st;

        // rotational messages: m_k = A*x + C, then rotate pairs by rot[e]
        float m[32];
        #pragma unroll
        for (int k = 0; k < 32; ++k)
            m[k] = fmaf(Am[k * NSEG + sm], x, Cm[k * NSEG + sm]);

        float* po = out_rot + (size_t)col * 32;
        #pragma unroll
        for (int j = 0; j < 16; ++j) {
            float m0 = m[2 * j], m1 = m[2 * j + 1];
            // rot[e] = [[c,-s],[s,c]] stored row-major as (r.x,r.y,r.z,r.w)
            atomicAdd(po + 2 * j,     fmaf(m0, r.x, m1 * r.z));
            atomicAdd(po + 2 * j + 1, fmaf(m0, r.y, m1 * r.w));
        }

        float* ps = out_sc + (size_t)col * 32;
        #pragma unroll
        for (int k = 0; k < 32; ++k)
            atomicAdd(ps + k, fmaf(As[k * NSEG + ss], x, Cs[k * NSEG + ss]));
    }
}

extern "C" void kernel_launch(void* const* d_in, const int* in_sizes, int n_in,
                              void* d_out, int out_size, void* d_ws, size_t ws_size,
                              hipStream_t stream) {
    const float* v      = (const float*)d_in[0];
    const float* rot    = (const float*)d_in[1];
    const int*   ei     = (const int*)d_in[2];
    const float* msg_w1 = (const float*)d_in[3];
    const float* msg_b1 = (const float*)d_in[4];
    const float* msg_w2 = (const float*)d_in[5];
    const float* msg_b2 = (const float*)d_in[6];
    const float* sc_w1  = (const float*)d_in[7];
    const float* sc_b1  = (const float*)d_in[8];
    const float* sc_w2  = (const float*)d_in[9];
    const float* sc_b2  = (const float*)d_in[10];

    const int E = in_sizes[0] / 2;    // v is [E,2]
    const int N = out_size / 64;      // out = N*32 scalars + N*32 rot floats

    float* ws  = (float*)d_ws;
    float* out = (float*)d_out;

    // output is accumulated into -> must zero every launch (harness poisons once)
    hipMemsetAsync(d_out, 0, (size_t)out_size * sizeof(float), stream);

    build_breakpoints<<<1, 192, 0, stream>>>(msg_w1, msg_b1, sc_w1, sc_b1, ws);
    build_tables<<<dim3(NSEG, 2), NOUT, 0, stream>>>(
        msg_w1, msg_b1, msg_w2, msg_b2, sc_w1, sc_b1, sc_w2, sc_b2, ws);
    edge_kernel<<<768, 256, 0, stream>>>(v, rot, ei, ws, out, E, N);
}

// Round 2
// 474.803 us; speedup vs baseline: 11.0607x; 11.0607x over previous
//
#include <hip/hip_runtime.h>

#define H     96    // hidden width of both MLPs
#define NOUT  32    // outputs of both MLPs
#define NSEG  97    // H+1 piecewise-linear segments
#define TPAD  128   // breakpoint array padded to pow2 for branchless search
#define TABSZ (NOUT * NSEG)   // 3104
#define TAB4  (4 * TABSZ)     // 12416 floats = all four tables

// ---- d_ws float-index layout -------------------------------------------
#define WS_TS_MSG   0
#define WS_TS_SC    128
#define WS_TAB      256        // A_msg | C_msg | A_sc | C_sc  (4 x 3104)
#define WS_RANK     12672      // int[192]
#define WS_CNT      16384      // int[N]      per-node edge counts
#define WS_BS       116480     // int[512]    block sums
#define WS_BSX      116992     // int[512]    exclusive-scanned block sums
#define WS_OFFS     117504     // int[N+1]    CSR offsets
#define WS_CUR      217856     // int[N]      scatter cursors
#define WS_PAY      317952     // float4[E]   sorted edge payloads

// ---------------------------------------------------------------------------
// P1: breakpoints t_j = -b1_j/w1_j, rank-sort, store sorted(+inf padded)+ranks
// ---------------------------------------------------------------------------
__global__ void build_breakpoints(const float* __restrict__ msg_w1,
                                  const float* __restrict__ msg_b1,
                                  const float* __restrict__ sc_w1,
                                  const float* __restrict__ sc_b1,
                                  float* __restrict__ ws) {
    __shared__ float t[2][H];
    const int tid = threadIdx.x;        // 192 threads
    const int mlp = tid / H;
    const int j   = tid % H;
    if (tid < 2 * H) {
        const float* w1 = mlp ? sc_w1 : msg_w1;
        const float* b1 = mlp ? sc_b1 : msg_b1;
        float w = w1[j], b = b1[j];
        t[mlp][j] = (w == 0.0f) ? __builtin_inff() : (-b / w);
    }
    __syncthreads();
    if (tid < 2 * H) {
        float tj = t[mlp][j];
        int r = 0;
        for (int i = 0; i < H; ++i) {
            float ti = t[mlp][i];
            r += (ti < tj) || (ti == tj && i < j);
        }
        float* ts = ws + (mlp ? WS_TS_SC : WS_TS_MSG);
        ts[r] = tj;
        ((int*)(ws + WS_RANK))[mlp * H + j] = r;
    }
    if (tid < 2 * (TPAD - H)) {
        int m2 = tid / (TPAD - H);
        int p  = tid % (TPAD - H);
        ws[m2 * TPAD + H + p] = __builtin_inff();
    }
}

// ---------------------------------------------------------------------------
// P2: per (segment, mlp): A,C such that mlp(x) = A*x + C on that segment
// ---------------------------------------------------------------------------
__global__ void build_tables(const float* __restrict__ msg_w1,
                             const float* __restrict__ msg_b1,
                             const float* __restrict__ msg_w2,
                             const float* __restrict__ msg_b2,
                             const float* __restrict__ sc_w1,
                             const float* __restrict__ sc_b1,
                             const float* __restrict__ sc_w2,
                             const float* __restrict__ sc_b2,
                             float* __restrict__ ws) {
    const int s   = blockIdx.x;   // 0..96
    const int mlp = blockIdx.y;   // 0,1
    const int k   = threadIdx.x;  // 0..31
    const float* w1 = mlp ? sc_w1 : msg_w1;
    const float* b1 = mlp ? sc_b1 : msg_b1;
    const float* w2 = mlp ? sc_w2 : msg_w2;
    const float* b2 = mlp ? sc_b2 : msg_b2;
    const int* rank = (const int*)(ws + WS_RANK) + mlp * H;
    float A = 0.0f, C = 0.0f;
    for (int j = 0; j < H; ++j) {
        float w = w1[j], b = b1[j];
        int   r = rank[j];
        bool active = (w > 0.0f) ? (r < s)
                    : (w < 0.0f) ? (r >= s)
                                 : (b > 0.0f);
        if (active) {
            float wk = w2[j * NOUT + k];
            A = fmaf(w, wk, A);
            C = fmaf(b, wk, C);
        }
    }
    float* At = ws + WS_TAB + mlp * (2 * TABSZ);
    float* Ct = At + TABSZ;
    At[k * NSEG + s] = A;
    Ct[k * NSEG + s] = C + b2[k];
}

// ---------------------------------------------------------------------------
// Sort pipeline: histogram -> 3-kernel exclusive scan -> scatter payloads
// ---------------------------------------------------------------------------
__global__ void hist_kernel(const int* __restrict__ col, int* __restrict__ cnt,
                            int E) {
    int e = blockIdx.x * blockDim.x + threadIdx.x;
    if (e < E) atomicAdd(&cnt[col[e]], 1);
}

__global__ void block_sums(const int* __restrict__ cnt, int* __restrict__ bs,
                           int N) {
    __shared__ int sh[256];
    int i = blockIdx.x * 256 + threadIdx.x;
    sh[threadIdx.x] = (i < N) ? cnt[i] : 0;
    __syncthreads();
    for (int off = 128; off > 0; off >>= 1) {
        if (threadIdx.x < off) sh[threadIdx.x] += sh[threadIdx.x + off];
        __syncthreads();
    }
    if (threadIdx.x == 0) bs[blockIdx.x] = sh[0];
}

__global__ void scan_bs(const int* __restrict__ bs, int* __restrict__ bsx,
                        int nb) {
    __shared__ int sh[512];
    int t = threadIdx.x;
    int v = (t < nb) ? bs[t] : 0;
    sh[t] = v;
    __syncthreads();
    for (int off = 1; off < 512; off <<= 1) {
        int u = (t >= off) ? sh[t - off] : 0;
        __syncthreads();
        sh[t] += u;
        __syncthreads();
    }
    if (t < nb) bsx[t] = sh[t] - v;   // exclusive
}

__global__ void block_scan(const int* __restrict__ cnt,
                           const int* __restrict__ bsx,
                           int* __restrict__ offs, int* __restrict__ cur,
                           int N, int E) {
    __shared__ int sh[256];
    int t = threadIdx.x;
    int i = blockIdx.x * 256 + t;
    int v = (i < N) ? cnt[i] : 0;
    sh[t] = v;
    __syncthreads();
    for (int off = 1; off < 256; off <<= 1) {
        int u = (t >= off) ? sh[t - off] : 0;
        __syncthreads();
        sh[t] += u;
        __syncthreads();
    }
    int excl = sh[t] - v + bsx[blockIdx.x];
    if (i < N) {
        offs[i] = excl;
        cur[i]  = excl;
        if (i == N - 1) offs[N] = excl + v;   // == E
    }
}

// payload = {x, int(sm | ss<<8), c, s}; rot = [[c,-s],[s,c]] so (c,s) suffice
__global__ __launch_bounds__(256) void scatter_kernel(
    const float* __restrict__ v, const float* __restrict__ rot,
    const int* __restrict__ col, const float* __restrict__ ws,
    int* __restrict__ cur, float4* __restrict__ pay, int E)
{
    __shared__ float ts_m[TPAD], ts_s[TPAD];
    for (int i = threadIdx.x; i < 2 * TPAD; i += blockDim.x) {
        float val = ws[i];
        if (i < TPAD) ts_m[i] = val; else ts_s[i - TPAD] = val;
    }
    __syncthreads();
    int e = blockIdx.x * blockDim.x + threadIdx.x;
    if (e >= E) return;
    float2 vv = *(const float2*)(v + 2 * (size_t)e);
    float  x  = sqrtf(vv.x * vv.x + vv.y * vv.y);
    float4 r  = *(const float4*)(rot + 4 * (size_t)e);
    int    c  = col[e];
    int sm = 0;
    #pragma unroll
    for (int st = 64; st > 0; st >>= 1) if (ts_m[sm + st - 1] < x) sm += st;
    int ss = 0;
    #pragma unroll
    for (int st = 64; st > 0; st >>= 1) if (ts_s[ss + st - 1] < x) ss += st;
    int pos = atomicAdd(&cur[c], 1);
    pay[pos] = make_float4(x, __int_as_float(sm | (ss << 8)), r.x, r.z);
}

// ---------------------------------------------------------------------------
// Gather: one wave per node, lane = one of 64 output components.
// lanes 0..31 -> scalar_features[k]; lanes 32..63 -> rot_features flat idx.
// ---------------------------------------------------------------------------
__global__ __launch_bounds__(256) void gather_kernel(
    const float4* __restrict__ pay, const int* __restrict__ offs,
    const float* __restrict__ ws, float* __restrict__ out, int N)
{
    __shared__ float tab[TAB4];
    {
        const float4* src = (const float4*)(ws + WS_TAB);
        float4* dst = (float4*)tab;
        for (int i = threadIdx.x; i < TAB4 / 4; i += blockDim.x) dst[i] = src[i];
    }
    __syncthreads();
    const float* Am = tab;
    const float* Cm = tab + TABSZ;
    const float* As = tab + 2 * TABSZ;
    const float* Cs = tab + 3 * TABSZ;

    int wave = blockIdx.x * (blockDim.x >> 6) + (threadIdx.x >> 6);
    int lane = threadIdx.x & 63;
    if (wave >= N) return;
    int beg = offs[wave], end = offs[wave + 1];

    bool is_sc = lane < 32;
    int  k     = lane & 31;       // scalar idx or rot flat idx
    int  j2    = k & ~1;          // rot: 2*j
    int  comp  = k & 1;

    float acc = 0.0f;
    for (int e = beg; e < end; ++e) {
        float4 p = pay[e];                 // uniform across wave -> broadcast
        float x = p.x;
        int   pk = __float_as_int(p.y);
        float c = p.z, s = p.w;
        float val;
        if (is_sc) {
            int ss = pk >> 8;
            val = fmaf(As[k * NSEG + ss], x, Cs[k * NSEG + ss]);
        } else {
            int sm = pk & 255;
            float m0 = fmaf(Am[j2 * NSEG + sm],       x, Cm[j2 * NSEG + sm]);
            float m1 = fmaf(Am[(j2 + 1) * NSEG + sm], x, Cm[(j2 + 1) * NSEG + sm]);
            val = comp ? fmaf(m1, c, -m0 * s) : fmaf(m0, c, m1 * s);
        }
        acc += val;
    }
    float* dst = is_sc ? (out + (size_t)wave * 32 + k)
                       : (out + (size_t)N * 32 + (size_t)wave * 32 + k);
    *dst = acc;
}

// ---------------------------------------------------------------------------
// Fallback (R1 path) if ws is too small for the sort pipeline
// ---------------------------------------------------------------------------
__global__ __launch_bounds__(256) void edge_kernel(
    const float* __restrict__ v, const float* __restrict__ rot,
    const int* __restrict__ ei, const float* __restrict__ ws,
    float* __restrict__ out, int E, int N)
{
    __shared__ float ts_m[TPAD], ts_s[TPAD];
    __shared__ float Am[TABSZ], Cm[TABSZ], As[TABSZ], Cs[TABSZ];
    for (int i = threadIdx.x; i < 256 + 4 * TABSZ; i += blockDim.x) {
        float val = ws[i];
        if      (i < 128)             ts_m[i]               = val;
        else if (i < 256)             ts_s[i - 128]         = val;
        else if (i < 256 + TABSZ)     Am[i - 256]           = val;
        else if (i < 256 + 2*TABSZ)   Cm[i - 256 - TABSZ]   = val;
        else if (i < 256 + 3*TABSZ)   As[i - 256 - 2*TABSZ] = val;
        else                          Cs[i - 256 - 3*TABSZ] = val;
    }
    __syncthreads();
    const int* col_idx = ei + E;
    float* out_sc  = out;
    float* out_rot = out + (size_t)N * 32;
    for (int e = blockIdx.x * blockDim.x + threadIdx.x; e < E;
         e += gridDim.x * blockDim.x) {
        float2 vv = *(const float2*)(v + 2 * (size_t)e);
        float  x  = sqrtf(vv.x * vv.x + vv.y * vv.y);
        float4 r  = *(const float4*)(rot + 4 * (size_t)e);
        int    col = col_idx[e];
        int sm = 0;
        #pragma unroll
        for (int st = 64; st > 0; st >>= 1) if (ts_m[sm + st - 1] < x) sm += st;
        int ss = 0;
        #pragma unroll
        for (int st = 64; st > 0; st >>= 1) if (ts_s[ss + st - 1] < x) ss += st;
        float m[32];
        #pragma unroll
        for (int k = 0; k < 32; ++k)
            m[k] = fmaf(Am[k * NSEG + sm], x, Cm[k * NSEG + sm]);
        float* po = out_rot + (size_t)col * 32;
        #pragma unroll
        for (int j = 0; j < 16; ++j) {
            float m0 = m[2 * j], m1 = m[2 * j + 1];
            atomicAdd(po + 2 * j,     fmaf(m0, r.x, m1 * r.z));
            atomicAdd(po + 2 * j + 1, fmaf(m0, r.y, m1 * r.w));
        }
        float* ps = out_sc + (size_t)col * 32;
        #pragma unroll
        for (int k = 0; k < 32; ++k)
            atomicAdd(ps + k, fmaf(As[k * NSEG + ss], x, Cs[k * NSEG + ss]));
    }
}

extern "C" void kernel_launch(void* const* d_in, const int* in_sizes, int n_in,
                              void* d_out, int out_size, void* d_ws, size_t ws_size,
                              hipStream_t stream) {
    const float* v      = (const float*)d_in[0];
    const float* rot    = (const float*)d_in[1];
    const int*   ei     = (const int*)d_in[2];
    const float* msg_w1 = (const float*)d_in[3];
    const float* msg_b1 = (const float*)d_in[4];
    const float* msg_w2 = (const float*)d_in[5];
    const float* msg_b2 = (const float*)d_in[6];
    const float* sc_w1  = (const float*)d_in[7];
    const float* sc_b1  = (const float*)d_in[8];
    const float* sc_w2  = (const float*)d_in[9];
    const float* sc_b2  = (const float*)d_in[10];

    const int E = in_sizes[0] / 2;    // v is [E,2]
    const int N = out_size / 64;      // out = N*32 scalars + N*32 rot floats

    float* ws  = (float*)d_ws;
    float* out = (float*)d_out;

    build_breakpoints<<<1, 192, 0, stream>>>(msg_w1, msg_b1, sc_w1, sc_b1, ws);
    build_tables<<<dim3(NSEG, 2), NOUT, 0, stream>>>(
        msg_w1, msg_b1, msg_w2, msg_b2, sc_w1, sc_b1, sc_w2, sc_b2, ws);

    size_t req = ((size_t)WS_PAY + 4 * (size_t)E) * 4;
    if (ws_size >= req) {
        int*    cnt  = (int*)(ws + WS_CNT);
        int*    bs   = (int*)(ws + WS_BS);
        int*    bsx  = (int*)(ws + WS_BSX);
        int*    offs = (int*)(ws + WS_OFFS);
        int*    cur  = (int*)(ws + WS_CUR);
        float4* pay  = (float4*)(ws + WS_PAY);
        hipMemsetAsync(cnt, 0, (size_t)N * sizeof(int), stream);
        hist_kernel<<<(E + 255) / 256, 256, 0, stream>>>(ei + E, cnt, E);
        int nb = (N + 255) / 256;
        block_sums<<<nb, 256, 0, stream>>>(cnt, bs, N);
        scan_bs<<<1, 512, 0, stream>>>(bs, bsx, nb);
        block_scan<<<nb, 256, 0, stream>>>(cnt, bsx, offs, cur, N, E);
        scatter_kernel<<<(E + 255) / 256, 256, 0, stream>>>(
            v, rot, ei + E, ws, cur, pay, E);
        gather_kernel<<<(N + 3) / 4, 256, 0, stream>>>(pay, offs, ws, out, N);
    } else {
        hipMemsetAsync(d_out, 0, (size_t)out_size * sizeof(float), stream);
        edge_kernel<<<768, 256, 0, stream>>>(v, rot, ei, ws, out, E, N);
    }
}

// Round 3
// 383.908 us; speedup vs baseline: 13.6794x; 1.2368x over previous
//
#include <hip/hip_runtime.h>

#define H     96    // hidden width of both MLPs
#define NOUT  32    // outputs of both MLPs
#define NSEG  97    // H+1 piecewise-linear segments
#define TPAD  128   // breakpoint array padded to pow2 for branchless search
#define ACSZ  (2 * NOUT * NSEG)   // 6208 floats: interleaved (A,C) table

// ---- d_ws float-index layout -------------------------------------------
#define WS_TS_MSG   0          // float[128] sorted breakpoints (+inf pad)
#define WS_TS_SC    128        // float[128]
#define WS_ACS      256        // float2[32][97]  scalar-MLP (A, C+b2)
#define WS_ACM      6464       // float4[16][97]  msg-MLP (A0,C0,A1,C1) pairs
#define WS_RANK     12672      // int[192]
#define WS_CNT      16384      // int[N]      per-node edge counts
#define WS_BS       116480     // int[512]    block sums
#define WS_BSX      116992     // int[512]    exclusive-scanned block sums
#define WS_OFFS     117504     // int[N+1]    CSR offsets
#define WS_CUR      217856     // int[N]      scatter cursors
#define WS_PAY      317952     // float4[E]   sorted edge payloads

// ---------------------------------------------------------------------------
// P1: breakpoints t_j = -b1_j/w1_j, rank-sort, store sorted(+inf padded)+ranks
// ---------------------------------------------------------------------------
__global__ void build_breakpoints(const float* __restrict__ msg_w1,
                                  const float* __restrict__ msg_b1,
                                  const float* __restrict__ sc_w1,
                                  const float* __restrict__ sc_b1,
                                  float* __restrict__ ws) {
    __shared__ float t[2][H];
    const int tid = threadIdx.x;        // 192 threads
    const int mlp = tid / H;
    const int j   = tid % H;
    if (tid < 2 * H) {
        const float* w1 = mlp ? sc_w1 : msg_w1;
        const float* b1 = mlp ? sc_b1 : msg_b1;
        float w = w1[j], b = b1[j];
        t[mlp][j] = (w == 0.0f) ? __builtin_inff() : (-b / w);
    }
    __syncthreads();
    if (tid < 2 * H) {
        float tj = t[mlp][j];
        int r = 0;
        for (int i = 0; i < H; ++i) {
            float ti = t[mlp][i];
            r += (ti < tj) || (ti == tj && i < j);
        }
        float* ts = ws + (mlp ? WS_TS_SC : WS_TS_MSG);
        ts[r] = tj;
        ((int*)(ws + WS_RANK))[mlp * H + j] = r;
    }
    if (tid < 2 * (TPAD - H)) {
        int m2 = tid / (TPAD - H);
        int p  = tid % (TPAD - H);
        ws[m2 * TPAD + H + p] = __builtin_inff();
    }
}

// ---------------------------------------------------------------------------
// P2: per (segment, mlp): A,C with mlp(x) = A*x + C on that segment.
// sc  -> ACs[k][s]       = (A, C+b2)           (float2, interleaved)
// msg -> ACm[k>>1][s]    = (A0,C0,A1,C1)       (float4, pair-interleaved)
// ---------------------------------------------------------------------------
__global__ void build_tables(const float* __restrict__ msg_w1,
                             const float* __restrict__ msg_b1,
                             const float* __restrict__ msg_w2,
                             const float* __restrict__ msg_b2,
                             const float* __restrict__ sc_w1,
                             const float* __restrict__ sc_b1,
                             const float* __restrict__ sc_w2,
                             const float* __restrict__ sc_b2,
                             float* __restrict__ ws) {
    const int s   = blockIdx.x;   // 0..96
    const int mlp = blockIdx.y;   // 0 = msg, 1 = sc
    const int k   = threadIdx.x;  // 0..31
    const float* w1 = mlp ? sc_w1 : msg_w1;
    const float* b1 = mlp ? sc_b1 : msg_b1;
    const float* w2 = mlp ? sc_w2 : msg_w2;
    const float* b2 = mlp ? sc_b2 : msg_b2;
    const int* rank = (const int*)(ws + WS_RANK) + mlp * H;
    float A = 0.0f, C = 0.0f;
    for (int j = 0; j < H; ++j) {
        float w = w1[j], b = b1[j];
        int   r = rank[j];
        bool active = (w > 0.0f) ? (r < s)
                    : (w < 0.0f) ? (r >= s)
                                 : (b > 0.0f);
        if (active) {
            float wk = w2[j * NOUT + k];
            A = fmaf(w, wk, A);
            C = fmaf(b, wk, C);
        }
    }
    C += b2[k];
    if (mlp) {
        float* dst = ws + WS_ACS + 2 * (k * NSEG + s);
        dst[0] = A; dst[1] = C;
    } else {
        float* dst = ws + WS_ACM + 4 * ((k >> 1) * NSEG + s) + 2 * (k & 1);
        dst[0] = A; dst[1] = C;
    }
}

// ---------------------------------------------------------------------------
// Sort pipeline: histogram -> 3-kernel exclusive scan -> scatter payloads
// ---------------------------------------------------------------------------
__global__ void hist_kernel(const int* __restrict__ col, int* __restrict__ cnt,
                            int E) {
    int e = blockIdx.x * blockDim.x + threadIdx.x;
    if (e < E) atomicAdd(&cnt[col[e]], 1);
}

__global__ void block_sums(const int* __restrict__ cnt, int* __restrict__ bs,
                           int N) {
    __shared__ int sh[256];
    int i = blockIdx.x * 256 + threadIdx.x;
    sh[threadIdx.x] = (i < N) ? cnt[i] : 0;
    __syncthreads();
    for (int off = 128; off > 0; off >>= 1) {
        if (threadIdx.x < off) sh[threadIdx.x] += sh[threadIdx.x + off];
        __syncthreads();
    }
    if (threadIdx.x == 0) bs[blockIdx.x] = sh[0];
}

__global__ void scan_bs(const int* __restrict__ bs, int* __restrict__ bsx,
                        int nb) {
    __shared__ int sh[512];
    int t = threadIdx.x;
    int v = (t < nb) ? bs[t] : 0;
    sh[t] = v;
    __syncthreads();
    for (int off = 1; off < 512; off <<= 1) {
        int u = (t >= off) ? sh[t - off] : 0;
        __syncthreads();
        sh[t] += u;
        __syncthreads();
    }
    if (t < nb) bsx[t] = sh[t] - v;   // exclusive
}

__global__ void block_scan(const int* __restrict__ cnt,
                           const int* __restrict__ bsx,
                           int* __restrict__ offs, int* __restrict__ cur,
                           int N, int E) {
    __shared__ int sh[256];
    int t = threadIdx.x;
    int i = blockIdx.x * 256 + t;
    int v = (i < N) ? cnt[i] : 0;
    sh[t] = v;
    __syncthreads();
    for (int off = 1; off < 256; off <<= 1) {
        int u = (t >= off) ? sh[t - off] : 0;
        __syncthreads();
        sh[t] += u;
        __syncthreads();
    }
    int excl = sh[t] - v + bsx[blockIdx.x];
    if (i < N) {
        offs[i] = excl;
        cur[i]  = excl;
        if (i == N - 1) offs[N] = excl + v;   // == E
    }
}

// payload = {x, int(sm | ss<<8), c, s}; rot = [[c,-s],[s,c]] so (c,s) suffice
__global__ __launch_bounds__(256) void scatter_kernel(
    const float* __restrict__ v, const float* __restrict__ rot,
    const int* __restrict__ col, const float* __restrict__ ws,
    int* __restrict__ cur, float4* __restrict__ pay, int E)
{
    __shared__ float ts_m[TPAD], ts_s[TPAD];
    for (int i = threadIdx.x; i < 2 * TPAD; i += blockDim.x) {
        float val = ws[i];
        if (i < TPAD) ts_m[i] = val; else ts_s[i - TPAD] = val;
    }
    __syncthreads();
    int e = blockIdx.x * blockDim.x + threadIdx.x;
    if (e >= E) return;
    float2 vv = *(const float2*)(v + 2 * (size_t)e);
    float  x  = sqrtf(vv.x * vv.x + vv.y * vv.y);
    float4 r  = *(const float4*)(rot + 4 * (size_t)e);
    int    c  = col[e];
    int sm = 0;
    #pragma unroll
    for (int st = 64; st > 0; st >>= 1) if (ts_m[sm + st - 1] < x) sm += st;
    int ss = 0;
    #pragma unroll
    for (int st = 64; st > 0; st >>= 1) if (ts_s[ss + st - 1] < x) ss += st;
    int pos = atomicAdd(&cur[c], 1);
    pay[pos] = make_float4(x, __int_as_float(sm | (ss << 8)), r.x, r.z);
}

// ---------------------------------------------------------------------------
// Gather: one wave per node. Lanes cooperatively load up to 64 payloads
// coalesced, then broadcast each edge via v_readlane (register-only).
// lanes 0..31 -> scalar_features[k]; lanes 32..63 -> rot_features flat k.
// ---------------------------------------------------------------------------
__device__ __forceinline__ float bcast_f(float v, int lane) {
    return __int_as_float(__builtin_amdgcn_readlane(__float_as_int(v), lane));
}

__global__ __launch_bounds__(256) void gather_kernel(
    const float4* __restrict__ pay, const int* __restrict__ offs,
    const float* __restrict__ ws, float* __restrict__ out, int N)
{
    __shared__ float acs[ACSZ];   // float2[32][97]
    __shared__ float acm[ACSZ];   // float4[16][97]
    {
        const float4* src = (const float4*)(ws + WS_ACS);
        float4* d1 = (float4*)acs;
        float4* d2 = (float4*)acm;
        for (int i = threadIdx.x; i < ACSZ / 4; i += blockDim.x) {
            d1[i] = src[i];
            d2[i] = src[ACSZ / 4 + i];
        }
    }
    __syncthreads();
    const float2* ACs = (const float2*)acs;
    const float4* ACm = (const float4*)acm;

    int wave = blockIdx.x * (blockDim.x >> 6) + (threadIdx.x >> 6);
    int lane = threadIdx.x & 63;
    if (wave >= N) return;
    int beg = offs[wave], end = offs[wave + 1];

    bool is_sc = lane < 32;
    int  k     = lane & 31;       // scalar idx or rot flat idx
    int  j     = k >> 1;          // rot pair index
    int  comp  = k & 1;

    float acc = 0.0f;
    for (int base = beg; base < end; base += 64) {
        int cnt = end - base;
        if (cnt > 64) cnt = 64;
        float4 p = make_float4(0.f, 0.f, 0.f, 0.f);
        if (lane < cnt) p = pay[base + lane];
        for (int e = 0; e < cnt; ++e) {
            float x  = bcast_f(p.x, e);
            int   pk = __builtin_amdgcn_readlane(__float_as_int(p.y), e);
            float c  = bcast_f(p.z, e);
            float s  = bcast_f(p.w, e);
            if (is_sc) {
                float2 ac = ACs[k * NSEG + (pk >> 8)];
                acc += fmaf(ac.x, x, ac.y);
            } else {
                float4 ac = ACm[j * NSEG + (pk & 255)];
                float m0 = fmaf(ac.x, x, ac.y);
                float m1 = fmaf(ac.z, x, ac.w);
                acc += comp ? fmaf(m1, c, -(m0 * s)) : fmaf(m0, c, m1 * s);
            }
        }
    }
    float* dst = is_sc ? (out + (size_t)wave * 32 + k)
                       : (out + (size_t)N * 32 + (size_t)wave * 32 + k);
    *dst = acc;
}

extern "C" void kernel_launch(void* const* d_in, const int* in_sizes, int n_in,
                              void* d_out, int out_size, void* d_ws, size_t ws_size,
                              hipStream_t stream) {
    const float* v      = (const float*)d_in[0];
    const float* rot    = (const float*)d_in[1];
    const int*   ei     = (const int*)d_in[2];
    const float* msg_w1 = (const float*)d_in[3];
    const float* msg_b1 = (const float*)d_in[4];
    const float* msg_w2 = (const float*)d_in[5];
    const float* msg_b2 = (const float*)d_in[6];
    const float* sc_w1  = (const float*)d_in[7];
    const float* sc_b1  = (const float*)d_in[8];
    const float* sc_w2  = (const float*)d_in[9];
    const float* sc_b2  = (const float*)d_in[10];

    const int E = in_sizes[0] / 2;    // v is [E,2]
    const int N = out_size / 64;      // out = N*32 scalars + N*32 rot floats

    float* ws  = (float*)d_ws;
    float* out = (float*)d_out;

    build_breakpoints<<<1, 192, 0, stream>>>(msg_w1, msg_b1, sc_w1, sc_b1, ws);
    build_tables<<<dim3(NSEG, 2), NOUT, 0, stream>>>(
        msg_w1, msg_b1, msg_w2, msg_b2, sc_w1, sc_b1, sc_w2, sc_b2, ws);

    int*    cnt  = (int*)(ws + WS_CNT);
    int*    bs   = (int*)(ws + WS_BS);
    int*    bsx  = (int*)(ws + WS_BSX);
    int*    offs = (int*)(ws + WS_OFFS);
    int*    cur  = (int*)(ws + WS_CUR);
    float4* pay  = (float4*)(ws + WS_PAY);

    hipMemsetAsync(cnt, 0, (size_t)N * sizeof(int), stream);
    hist_kernel<<<(E + 255) / 256, 256, 0, stream>>>(ei + E, cnt, E);
    int nb = (N + 255) / 256;
    block_sums<<<nb, 256, 0, stream>>>(cnt, bs, N);
    scan_bs<<<1, 512, 0, stream>>>(bs, bsx, nb);
    block_scan<<<nb, 256, 0, stream>>>(cnt, bsx, offs, cur, N, E);
    scatter_kernel<<<(E + 255) / 256, 256, 0, stream>>>(
        v, rot, ei + E, ws, cur, pay, E);
    gather_kernel<<<(N + 3) / 4, 256, 0, stream>>>(pay, offs, ws, out, N);
}

// Round 4
// 323.148 us; speedup vs baseline: 16.2515x; 1.1880x over previous
//
#include <hip/hip_runtime.h>

#define H     96    // hidden width of both MLPs
#define NOUT  32    // outputs of both MLPs
#define NSEG  97    // H+1 piecewise-linear segments
#define TPAD  128   // breakpoint array padded to pow2 for branchless search
#define TABF  6208  // floats per table (scalar: float2[97][32], msg: float4[97][16])

// ---- d_ws float-index layout -------------------------------------------
#define WS_TS_MSG   0          // float[128] sorted breakpoints (+inf pad)
#define WS_TS_SC    128        // float[128]
#define WS_ACS      256        // float2[97][32]  scalar-MLP (A, C+b2), [s][k]
#define WS_ACM      6464       // float4[97][16]  msg-MLP (A0,C0,A1,C1), [s][j]
#define WS_RANK     12672      // int[192]
#define WS_CNT      16384      // int[N]      per-node edge counts
#define WS_BS       116480     // int[512]    block sums
#define WS_BSX      116992     // int[512]    exclusive-scanned block sums
#define WS_OFFS     117504     // int[N+1]    CSR offsets
#define WS_CUR      217856     // int[N]      scatter cursors
#define WS_PAY      317952     // float4[E]   sorted edge payloads

// ---------------------------------------------------------------------------
// P1: breakpoints t_j = -b1_j/w1_j, rank-sort, store sorted(+inf padded)+ranks
// ---------------------------------------------------------------------------
__global__ void build_breakpoints(const float* __restrict__ msg_w1,
                                  const float* __restrict__ msg_b1,
                                  const float* __restrict__ sc_w1,
                                  const float* __restrict__ sc_b1,
                                  float* __restrict__ ws) {
    __shared__ float t[2][H];
    const int tid = threadIdx.x;        // 192 threads
    const int mlp = tid / H;
    const int j   = tid % H;
    if (tid < 2 * H) {
        const float* w1 = mlp ? sc_w1 : msg_w1;
        const float* b1 = mlp ? sc_b1 : msg_b1;
        float w = w1[j], b = b1[j];
        t[mlp][j] = (w == 0.0f) ? __builtin_inff() : (-b / w);
    }
    __syncthreads();
    if (tid < 2 * H) {
        float tj = t[mlp][j];
        int r = 0;
        for (int i = 0; i < H; ++i) {
            float ti = t[mlp][i];
            r += (ti < tj) || (ti == tj && i < j);
        }
        float* ts = ws + (mlp ? WS_TS_SC : WS_TS_MSG);
        ts[r] = tj;
        ((int*)(ws + WS_RANK))[mlp * H + j] = r;
    }
    if (tid < 2 * (TPAD - H)) {
        int m2 = tid / (TPAD - H);
        int p  = tid % (TPAD - H);
        ws[m2 * TPAD + H + p] = __builtin_inff();
    }
}

// ---------------------------------------------------------------------------
// P2: per (segment, mlp): A,C with mlp(x) = A*x + C on that segment.
// sc  -> ws[WS_ACS + 2*(s*32+k)]           = (A, C+b2)       [s][k] float2
// msg -> ws[WS_ACM + 4*(s*16+j) + 2*comp]  = (A, C+b2)       [s][j] float4
// ---------------------------------------------------------------------------
__global__ void build_tables(const float* __restrict__ msg_w1,
                             const float* __restrict__ msg_b1,
                             const float* __restrict__ msg_w2,
                             const float* __restrict__ msg_b2,
                             const float* __restrict__ sc_w1,
                             const float* __restrict__ sc_b1,
                             const float* __restrict__ sc_w2,
                             const float* __restrict__ sc_b2,
                             float* __restrict__ ws) {
    const int s   = blockIdx.x;   // 0..96
    const int mlp = blockIdx.y;   // 0 = msg, 1 = sc
    const int k   = threadIdx.x;  // 0..31
    const float* w1 = mlp ? sc_w1 : msg_w1;
    const float* b1 = mlp ? sc_b1 : msg_b1;
    const float* w2 = mlp ? sc_w2 : msg_w2;
    const float* b2 = mlp ? sc_b2 : msg_b2;
    const int* rank = (const int*)(ws + WS_RANK) + mlp * H;
    float A = 0.0f, C = 0.0f;
    for (int j = 0; j < H; ++j) {
        float w = w1[j], b = b1[j];
        int   r = rank[j];
        bool active = (w > 0.0f) ? (r < s)
                    : (w < 0.0f) ? (r >= s)
                                 : (b > 0.0f);
        if (active) {
            float wk = w2[j * NOUT + k];
            A = fmaf(w, wk, A);
            C = fmaf(b, wk, C);
        }
    }
    C += b2[k];
    if (mlp) {
        float* dst = ws + WS_ACS + 2 * (s * 32 + k);
        dst[0] = A; dst[1] = C;
    } else {
        float* dst = ws + WS_ACM + 4 * (s * 16 + (k >> 1)) + 2 * (k & 1);
        dst[0] = A; dst[1] = C;
    }
}

// ---------------------------------------------------------------------------
// Sort pipeline: histogram -> 3-kernel exclusive scan -> scatter payloads
// ---------------------------------------------------------------------------
__global__ void hist_kernel(const int* __restrict__ col, int* __restrict__ cnt,
                            int E) {
    int e = blockIdx.x * blockDim.x + threadIdx.x;
    if (e < E) atomicAdd(&cnt[col[e]], 1);
}

__global__ void block_sums(const int* __restrict__ cnt, int* __restrict__ bs,
                           int N) {
    __shared__ int sh[256];
    int i = blockIdx.x * 256 + threadIdx.x;
    sh[threadIdx.x] = (i < N) ? cnt[i] : 0;
    __syncthreads();
    for (int off = 128; off > 0; off >>= 1) {
        if (threadIdx.x < off) sh[threadIdx.x] += sh[threadIdx.x + off];
        __syncthreads();
    }
    if (threadIdx.x == 0) bs[blockIdx.x] = sh[0];
}

__global__ void scan_bs(const int* __restrict__ bs, int* __restrict__ bsx,
                        int nb) {
    __shared__ int sh[512];
    int t = threadIdx.x;
    int v = (t < nb) ? bs[t] : 0;
    sh[t] = v;
    __syncthreads();
    for (int off = 1; off < 512; off <<= 1) {
        int u = (t >= off) ? sh[t - off] : 0;
        __syncthreads();
        sh[t] += u;
        __syncthreads();
    }
    if (t < nb) bsx[t] = sh[t] - v;   // exclusive
}

__global__ void block_scan(const int* __restrict__ cnt,
                           const int* __restrict__ bsx,
                           int* __restrict__ offs, int* __restrict__ cur,
                           int N, int E) {
    __shared__ int sh[256];
    int t = threadIdx.x;
    int i = blockIdx.x * 256 + t;
    int v = (i < N) ? cnt[i] : 0;
    sh[t] = v;
    __syncthreads();
    for (int off = 1; off < 256; off <<= 1) {
        int u = (t >= off) ? sh[t - off] : 0;
        __syncthreads();
        sh[t] += u;
        __syncthreads();
    }
    int excl = sh[t] - v + bsx[blockIdx.x];
    if (i < N) {
        offs[i] = excl;
        cur[i]  = excl;
        if (i == N - 1) offs[N] = excl + v;   // == E
    }
}

// payload = {x, int(sm | ss<<8), c, s}; rot = [[c,-s],[s,c]] so (c,s) suffice
__global__ __launch_bounds__(256) void scatter_kernel(
    const float* __restrict__ v, const float* __restrict__ rot,
    const int* __restrict__ col, const float* __restrict__ ws,
    int* __restrict__ cur, float4* __restrict__ pay, int E)
{
    __shared__ float ts_m[TPAD], ts_s[TPAD];
    for (int i = threadIdx.x; i < 2 * TPAD; i += blockDim.x) {
        float val = ws[i];
        if (i < TPAD) ts_m[i] = val; else ts_s[i - TPAD] = val;
    }
    __syncthreads();
    int e = blockIdx.x * blockDim.x + threadIdx.x;
    if (e >= E) return;
    float2 vv = *(const float2*)(v + 2 * (size_t)e);
    float  x  = sqrtf(vv.x * vv.x + vv.y * vv.y);
    float4 r  = *(const float4*)(rot + 4 * (size_t)e);
    int    c  = col[e];
    int sm = 0;
    #pragma unroll
    for (int st = 64; st > 0; st >>= 1) if (ts_m[sm + st - 1] < x) sm += st;
    int ss = 0;
    #pragma unroll
    for (int st = 64; st > 0; st >>= 1) if (ts_s[ss + st - 1] < x) ss += st;
    int pos = atomicAdd(&cur[c], 1);
    pay[pos] = make_float4(x, __int_as_float(sm | (ss << 8)), r.x, r.z);
}

// ---------------------------------------------------------------------------
// Gather, fused dual-mode: blockIdx.y = 0 -> scalar outputs, 1 -> rot outputs.
// Wave = node. Lanes = 32 outputs x 2 edge-slots (half = lane>>5).
// Payload chunk (<=64 edges) staged in per-wave LDS; each half-wave
// broadcasts edge 2t+half; cross-half reduce via shfl_xor(32) at the end.
// LDS = 24832 (one table) + 4096 (paybuf) = 28928 B -> 5 blocks/CU.
// ---------------------------------------------------------------------------
__global__ __launch_bounds__(256) void gather_kernel(
    const float4* __restrict__ pay, const int* __restrict__ offs,
    const float* __restrict__ ws, float* __restrict__ out, int N)
{
    __shared__ float4 tabv[TABF / 4];     // 24832 B
    __shared__ float4 paybuf[4][64];      //  4096 B
    const int mode = blockIdx.y;          // 0 = scalar, 1 = rot
    {
        const float4* src = (const float4*)(ws + (mode ? WS_ACM : WS_ACS));
        for (int i = threadIdx.x; i < TABF / 4; i += blockDim.x)
            tabv[i] = src[i];
    }
    __syncthreads();

    const int wv   = threadIdx.x >> 6;
    const int lane = threadIdx.x & 63;
    const int node = blockIdx.x * 4 + wv;
    if (node >= N) return;
    const int beg = offs[node], end = offs[node + 1];
    const int k    = lane & 31;
    const int half = lane >> 5;
    float4* pb = paybuf[wv];

    pb[lane] = make_float4(0.f, 0.f, 0.f, 0.f);   // safe pk for invalid slots

    float acc = 0.f, acc2 = 0.f;

    if (mode == 0) {
        const float2* t2 = (const float2*)tabv;
        for (int base = beg; base < end; base += 64) {
            int cnt = end - base; if (cnt > 64) cnt = 64;
            if (lane < cnt) pb[lane] = pay[base + lane];
            __threadfence_block();
            int tmax = (cnt + 1) >> 1;
            int t = 0;
            for (; t + 2 <= tmax; t += 2) {
                int e0 = 2 * t + half, e1 = e0 + 2;
                float4 p0 = pb[e0];
                float4 p1 = pb[e1];
                float2 a0 = t2[(__float_as_int(p0.y) >> 8) * 32 + k];
                float2 a1 = t2[(__float_as_int(p1.y) >> 8) * 32 + k];
                float v0 = fmaf(a0.x, p0.x, a0.y);
                float v1 = fmaf(a1.x, p1.x, a1.y);
                acc  += (e0 < cnt) ? v0 : 0.f;
                acc2 += (e1 < cnt) ? v1 : 0.f;
            }
            if (t < tmax) {
                int e0 = 2 * t + half;
                float4 p0 = pb[e0];
                float2 a0 = t2[(__float_as_int(p0.y) >> 8) * 32 + k];
                float v0 = fmaf(a0.x, p0.x, a0.y);
                acc += (e0 < cnt) ? v0 : 0.f;
            }
            __threadfence_block();
        }
    } else {
        const float4* t4 = tabv;
        const int j = k >> 1, comp = k & 1;
        for (int base = beg; base < end; base += 64) {
            int cnt = end - base; if (cnt > 64) cnt = 64;
            if (lane < cnt) pb[lane] = pay[base + lane];
            __threadfence_block();
            int tmax = (cnt + 1) >> 1;
            int t = 0;
            for (; t + 2 <= tmax; t += 2) {
                int e0 = 2 * t + half, e1 = e0 + 2;
                float4 p0 = pb[e0];
                float4 p1 = pb[e1];
                float4 a0 = t4[(__float_as_int(p0.y) & 255) * 16 + j];
                float4 a1 = t4[(__float_as_int(p1.y) & 255) * 16 + j];
                float m00 = fmaf(a0.x, p0.x, a0.y);
                float m01 = fmaf(a0.z, p0.x, a0.w);
                float m10 = fmaf(a1.x, p1.x, a1.y);
                float m11 = fmaf(a1.z, p1.x, a1.w);
                float v0 = comp ? fmaf(m01, p0.z, -(m00 * p0.w))
                                : fmaf(m00, p0.z, m01 * p0.w);
                float v1 = comp ? fmaf(m11, p1.z, -(m10 * p1.w))
                                : fmaf(m10, p1.z, m11 * p1.w);
                acc  += (e0 < cnt) ? v0 : 0.f;
                acc2 += (e1 < cnt) ? v1 : 0.f;
            }
            if (t < tmax) {
                int e0 = 2 * t + half;
                float4 p0 = pb[e0];
                float4 a0 = t4[(__float_as_int(p0.y) & 255) * 16 + j];
                float m00 = fmaf(a0.x, p0.x, a0.y);
                float m01 = fmaf(a0.z, p0.x, a0.w);
                float v0 = comp ? fmaf(m01, p0.z, -(m00 * p0.w))
                                : fmaf(m00, p0.z, m01 * p0.w);
                acc += (e0 < cnt) ? v0 : 0.f;
            }
            __threadfence_block();
        }
    }

    acc += acc2;
    acc += __shfl_xor(acc, 32, 64);
    if (half == 0) {
        float* dst = out + (mode ? (size_t)N * 32 : 0) + (size_t)node * 32 + k;
        *dst = acc;
    }
}

extern "C" void kernel_launch(void* const* d_in, const int* in_sizes, int n_in,
                              void* d_out, int out_size, void* d_ws, size_t ws_size,
                              hipStream_t stream) {
    const float* v      = (const float*)d_in[0];
    const float* rot    = (const float*)d_in[1];
    const int*   ei     = (const int*)d_in[2];
    const float* msg_w1 = (const float*)d_in[3];
    const float* msg_b1 = (const float*)d_in[4];
    const float* msg_w2 = (const float*)d_in[5];
    const float* msg_b2 = (const float*)d_in[6];
    const float* sc_w1  = (const float*)d_in[7];
    const float* sc_b1  = (const float*)d_in[8];
    const float* sc_w2  = (const float*)d_in[9];
    const float* sc_b2  = (const float*)d_in[10];

    const int E = in_sizes[0] / 2;    // v is [E,2]
    const int N = out_size / 64;      // out = N*32 scalars + N*32 rot floats

    float* ws  = (float*)d_ws;
    float* out = (float*)d_out;

    build_breakpoints<<<1, 192, 0, stream>>>(msg_w1, msg_b1, sc_w1, sc_b1, ws);
    build_tables<<<dim3(NSEG, 2), NOUT, 0, stream>>>(
        msg_w1, msg_b1, msg_w2, msg_b2, sc_w1, sc_b1, sc_w2, sc_b2, ws);

    int*    cnt  = (int*)(ws + WS_CNT);
    int*    bs   = (int*)(ws + WS_BS);
    int*    bsx  = (int*)(ws + WS_BSX);
    int*    offs = (int*)(ws + WS_OFFS);
    int*    cur  = (int*)(ws + WS_CUR);
    float4* pay  = (float4*)(ws + WS_PAY);

    hipMemsetAsync(cnt, 0, (size_t)N * sizeof(int), stream);
    hist_kernel<<<(E + 255) / 256, 256, 0, stream>>>(ei + E, cnt, E);
    int nb = (N + 255) / 256;
    block_sums<<<nb, 256, 0, stream>>>(cnt, bs, N);
    scan_bs<<<1, 512, 0, stream>>>(bs, bsx, nb);
    block_scan<<<nb, 256, 0, stream>>>(cnt, bsx, offs, cur, N, E);
    scatter_kernel<<<(E + 255) / 256, 256, 0, stream>>>(
        v, rot, ei + E, ws, cur, pay, E);
    gather_kernel<<<dim3((N + 3) / 4, 2), 256, 0, stream>>>(pay, offs, ws, out, N);
}